// Round 15
// baseline (1236.650 us; speedup 1.0000x reference)
//
#include <hip/hip_runtime.h>
#include <math.h>

#define HD  256
#define BM  16
#define NTH 256
#define TPB 4    // tiles per persistent block

typedef __attribute__((ext_vector_type(8))) short bf16x8;
typedef __attribute__((ext_vector_type(4))) float f32x4;

__device__ __forceinline__ float rcp_f(float x){ return __builtin_amdgcn_rcpf(x); }
__device__ __forceinline__ float tanh_f(float x){
  float ax = fabsf(x);
  float e  = __expf(-2.f*ax);
  float t  = (1.f - e) * rcp_f(1.f + e);
  return copysignf(t, x);
}
__device__ __forceinline__ float artanh_f(float v){
  v = fminf(fmaxf(v, -1.f + 1e-7f), 1.f - 1e-7f);
  return 0.5f * __logf((1.f + v) * rcp_f(1.f - v));
}
__device__ __forceinline__ float sigmoid_f(float v){ return rcp_f(1.f + __expf(-v)); }
__device__ __forceinline__ unsigned short f2bf(float f){
  unsigned u = __float_as_uint(f);
  u += 0x7FFFu + ((u >> 16) & 1u);
  return (unsigned short)(u >> 16);
}
__device__ __forceinline__ float bf2f(unsigned short h){
  return __uint_as_float(((unsigned)h) << 16);
}
__device__ __forceinline__ int swz(int R, int C){
  return R*HD + (((C >> 3) ^ (R & 7)) << 3) + (C & 7);
}

// ---- 16-lane row-sum via DPP row_ror (pure VALU; R13's proven win) ----
__device__ __forceinline__ float sum16_dpp(float v){
  v += __uint_as_float((unsigned)__builtin_amdgcn_update_dpp(
        0, (int)__float_as_uint(v), 0x121, 0xF, 0xF, false)); // row_ror:1
  v += __uint_as_float((unsigned)__builtin_amdgcn_update_dpp(
        0, (int)__float_as_uint(v), 0x122, 0xF, 0xF, false)); // row_ror:2
  v += __uint_as_float((unsigned)__builtin_amdgcn_update_dpp(
        0, (int)__float_as_uint(v), 0x124, 0xF, 0xF, false)); // row_ror:4
  v += __uint_as_float((unsigned)__builtin_amdgcn_update_dpp(
        0, (int)__float_as_uint(v), 0x128, 0xF, 0xF, false)); // row_ror:8
  return v;
}

// ---- W fp32 -> bf16 in MFMA-fragment order ----
__global__ void convert_w_kernel(const float* __restrict__ Wih,
                                 const float* __restrict__ Whh,
                                 unsigned short* __restrict__ wb){
  int c = blockIdx.x * blockDim.x + threadIdx.x;
  if (c >= 6 * 8192) return;
  int mat = c >> 13;
  int ci  = c & 8191;
  int l = ci & 63, st = ci >> 6;
  int s = st & 7, ct = st >> 3;
  int col = ct * 16 + (l & 15);
  int k0  = s * 32 + (l >> 4) * 8;
  const float* src = (mat < 3) ? (Wih + (size_t)mat * HD * HD)
                               : (Whh + (size_t)(mat - 3) * HD * HD);
  const float* p = src + (size_t)col * HD + k0;
  unsigned short tmp[8];
  #pragma unroll
  for (int j = 0; j < 8; ++j) tmp[j] = f2bf(p[j]);
  *(bf16x8*)(wb + (size_t)mat * 65536 + (size_t)ci * 8) = *(bf16x8*)tmp;
}

// ---- 7-value reduction for one (A,B) gate pair -> RED[R][wc*8+j], j=0..6 ----
__device__ __forceinline__ void reduce7(
    const f32x4* A, const f32x4* B, const float* bt,
    float (*RED)[33], int wc, int lr, int lg){
  float p[7][4];
  #pragma unroll
  for (int q = 0; q < 4; ++q){
    float a2=0.f,b2=0.f,ab=0.f,sA=0.f,sB=0.f,Ab=0.f,Bb=0.f;
    #pragma unroll
    for (int n = 0; n < 4; ++n){
      float ae = A[n][q], be = B[n][q], bv = bt[n];
      a2 = fmaf(ae,ae,a2); b2 = fmaf(be,be,b2); ab = fmaf(ae,be,ab);
      sA += ae; sB += be; Ab = fmaf(ae,bv,Ab); Bb = fmaf(be,bv,Bb);
    }
    p[0][q]=a2; p[1][q]=b2; p[2][q]=ab; p[3][q]=sA; p[4][q]=sB; p[5][q]=Ab; p[6][q]=Bb;
  }
  #pragma unroll
  for (int j = 0; j < 7; ++j)
    #pragma unroll
    for (int q = 0; q < 4; ++q)
      p[j][q] = sum16_dpp(p[j][q]);
  if (lr == 0){
    #pragma unroll
    for (int q = 0; q < 4; ++q){
      int R = lg*4 + q;
      #pragma unroll
      for (int j = 0; j < 7; ++j) RED[R][wc*8 + j] = p[j][q];
    }
  }
}

// ---- once-per-row mobius+LN chain: s[7] -> {KA,KB,Kb,mu,is} ----
__device__ __forceinline__ void chain5(
    const float* s, float bb, float sbs,
    float an, float aa, float bn, float ba, float* o){
  float mraw = sqrtf(s[0]); float mA = fmaxf(mraw, 1e-7f);
  float tA = tanh_f(mA / an * aa);
  float sa  = (mraw <= 1e-7f) ? 0.f : tA / mA;
  float x2a = (mraw <= 1e-7f) ? 0.f : tA*tA;
  float nraw = sqrtf(s[1]); float mB = fmaxf(nraw, 1e-7f);
  float tB = tanh_f(mB / bn * ba);
  float sb_ = (nraw <= 1e-7f) ? 0.f : tB / mB;
  float x2b = (nraw <= 1e-7f) ? 0.f : tB*tB;
  float xy = sa*sb_*s[2];
  float ca = 1.f + 2.f*xy + x2b;
  float cb = 1.f - x2a;
  float den = fmaxf(1.f + 2.f*xy + x2a*x2b, 1e-15f);
  float u = ca*sa/den, v = cb*sb_/den;
  float P2 = u*u*s[0] + 2.f*u*v*s[2] + v*v*s[1];
  float Pb = u*s[5] + v*s[6];
  float sP = u*s[3] + v*s[4];
  float ca2 = 1.f + 2.f*Pb + bb;
  float cb2 = 1.f - P2;
  float den2 = fmaxf(1.f + 2.f*Pb + P2*bb, 1e-15f);
  float pp = ca2/den2, ww = cb2/den2;
  float Q2 = pp*pp*P2 + 2.f*pp*ww*Pb + ww*ww*bb;
  float sQsum = pp*sP + ww*sbs;
  float qn = fmaxf(sqrtf(Q2), 1e-7f);
  float sQ = artanh_f(qn) / qn;
  float mu = sQ*sQsum*(1.f/HD);
  float e2 = sQ*sQ*Q2*(1.f/HD);
  float is = rsqrtf(e2 - mu*mu + 1e-5f);
  o[0] = sQ*pp*u;  o[1] = sQ*pp*v;  o[2] = sQ*ww;
  o[3] = mu;       o[4] = is;
}

// R14's persistent-block idea with the spill bug fixed: `#pragma unroll 1`
// on the tile loop. R14 omitted it, the compiler fully unrolled TPB=4 ->
// 4 interleaved tile bodies, cross-tile live ranges, VGPR 128 cap + 1.6 GB
// scratch FETCH. Rolled loop keeps register pressure identical to R13
// (only sbb in LDS + loop index persist across tiles). Bias stats hoisted;
// setup/drain amortized 4x; no loop-end barrier (staging writes xb/hb/
// spart(REDZ); stragglers read kco+regs — disjoint).
__global__ __launch_bounds__(NTH, 2) void mobius_gru_mfma(
    const float* __restrict__ x, const float* __restrict__ hx,
    const unsigned short* __restrict__ wbih, const unsigned short* __restrict__ wbhh,
    const float* __restrict__ bias, const float* __restrict__ gam,
    const float* __restrict__ bet, float* __restrict__ out, int B){
  __shared__ unsigned short xb[BM*HD];
  __shared__ unsigned short hb[BM*HD];
  __shared__ float REDZ[BM][33];
  __shared__ float REDR[BM][33];
  __shared__ float kco[BM][10];   // z: 0..4, r: 5..9 (h reuses 0..4)
  __shared__ float srow[8][BM];   // 0:xn 1:xa 2:hn 3:ha 4:rn 5:ra 6:htn 7:hta
  __shared__ float sbb[8];        // [g]=sum b^2, [4+g]=sum b

  const int t  = threadIdx.x;
  const int l  = t & 63;
  const int lr = l & 15, lg = l >> 4;
  const int wc = t >> 6;          // 4 waves, one 64-col slice each

  // ---- bias row stats: ONCE per persistent block (visible after 1st barrier)
  if (t >= 64 && t < 256){
    int g = (t >> 6) - 1;
    float4 b4 = *(const float4*)&bias[g*HD + (t & 63)*4];
    float p2 = b4.x*b4.x + b4.y*b4.y + b4.z*b4.z + b4.w*b4.w;
    float ps = b4.x + b4.y + b4.z + b4.w;
    #pragma unroll
    for (int m = 1; m <= 32; m <<= 1){ p2 += __shfl_xor(p2, m); ps += __shfl_xor(ps, m); }
    if ((t & 63) == 0){ sbb[g] = p2; sbb[4+g] = ps; }
  }

  #pragma unroll 1
  for (int tile = 0; tile < TPB; ++tile){
    const size_t row0 = ((size_t)blockIdx.x * TPB + tile) * BM;

    // ---- stage x,hx -> bf16 swizzled LDS + norm partials (spart overlays REDZ) ----
    {
      float* spart = &REDZ[0][0];   // [0,256): x partials, [256,512): h partials
      int r = t >> 4, seg = t & 15;
      const float* xp = x  + (row0 + r)*HD + seg*16;
      const float* hp = hx + (row0 + r)*HD + seg*16;
      float sx = 0.f, sh = 0.f;
      #pragma unroll
      for (int i = 0; i < 4; ++i){
        int c = seg*16 + i*4;
        int di = swz(r, c);
        float4 v = *(const float4*)(xp + i*4);
        sx += v.x*v.x + v.y*v.y + v.z*v.z + v.w*v.w;
        ushort4 o = { f2bf(v.x), f2bf(v.y), f2bf(v.z), f2bf(v.w) };
        *(ushort4*)&xb[di] = o;
        v = *(const float4*)(hp + i*4);
        sh += v.x*v.x + v.y*v.y + v.z*v.z + v.w*v.w;
        ushort4 o2 = { f2bf(v.x), f2bf(v.y), f2bf(v.z), f2bf(v.w) };
        *(ushort4*)&hb[di] = o2;
      }
      spart[r*16 + seg] = sx; spart[256 + r*16 + seg] = sh;
    }
    __syncthreads();
    if (t < BM){
      float* spart = &REDZ[0][0];
      float sx = 0.f, sh = 0.f;
      #pragma unroll
      for (int i = 0; i < 16; ++i){ sx += spart[t*16 + i]; sh += spart[256 + t*16 + i]; }
      float xn = fmaxf(sqrtf(sx), 1e-7f);
      float hn = fmaxf(sqrtf(sh), 1e-7f);
      srow[0][t] = xn; srow[1][t] = artanh_f(xn);
      srow[2][t] = hn; srow[3][t] = artanh_f(hn);
    }
    __syncthreads();

    // ================= fused z + r + x-of-h GEMM (5 weight streams) =========
    f32x4 Az[4], Bz[4], Ar[4], Br[4], Bh[4];
    float btz[4], btr[4];
    #pragma unroll
    for (int n = 0; n < 4; ++n){
      int C = wc*64 + n*16 + lr;
      btz[n] = bias[2*HD + C];
      btr[n] = bias[C];
      Az[n] = (f32x4){0.f,0.f,0.f,0.f}; Bz[n] = (f32x4){0.f,0.f,0.f,0.f};
      Ar[n] = (f32x4){0.f,0.f,0.f,0.f}; Br[n] = (f32x4){0.f,0.f,0.f,0.f};
      Bh[n] = (f32x4){0.f,0.f,0.f,0.f};
    }
    {
      const unsigned short* wHz = wbhh + 2*65536;
      const unsigned short* wXz = wbih + 2*65536;
      const unsigned short* wHr = wbhh;
      const unsigned short* wXr = wbih;
      const unsigned short* wXh = wbih + 65536;
      #pragma unroll
      for (int s = 0; s < 8; ++s){
        int idx = lr*HD + (((4*s + lg) ^ (lr & 7)) << 3);
        bf16x8 ah = *(const bf16x8*)&hb[idx];
        bf16x8 ax = *(const bf16x8*)&xb[idx];
        #pragma unroll
        for (int n = 0; n < 4; ++n){
          int off = (((wc*4 + n)*8 + s)*64 + l)*8;
          bf16x8 bhz = *(const bf16x8*)(wHz + off);
          bf16x8 bxz = *(const bf16x8*)(wXz + off);
          bf16x8 bhr = *(const bf16x8*)(wHr + off);
          bf16x8 bxr = *(const bf16x8*)(wXr + off);
          bf16x8 bxh = *(const bf16x8*)(wXh + off);
          Az[n] = __builtin_amdgcn_mfma_f32_16x16x32_bf16(ah, bhz, Az[n], 0, 0, 0);
          Bz[n] = __builtin_amdgcn_mfma_f32_16x16x32_bf16(ax, bxz, Bz[n], 0, 0, 0);
          Ar[n] = __builtin_amdgcn_mfma_f32_16x16x32_bf16(ah, bhr, Ar[n], 0, 0, 0);
          Br[n] = __builtin_amdgcn_mfma_f32_16x16x32_bf16(ax, bxr, Br[n], 0, 0, 0);
          Bh[n] = __builtin_amdgcn_mfma_f32_16x16x32_bf16(ax, bxh, Bh[n], 0, 0, 0);
        }
      }
    }
    reduce7(Az, Bz, btz, REDZ, wc, lr, lg);
    reduce7(Ar, Br, btr, REDR, wc, lr, lg);
    __syncthreads();
    // z chain on t<16, r chain on 16<=t<32 — same code path, disjoint threads
    if (t < 32){
      int R = t & 15, gsel = t >> 4;            // 0: z (gidx 2), 1: r (gidx 0)
      float (*REDp)[33] = gsel ? REDR : REDZ;
      int gidx = gsel ? 0 : 2;
      float s[7];
      #pragma unroll
      for (int j = 0; j < 7; ++j)
        s[j] = REDp[R][j] + REDp[R][8+j] + REDp[R][16+j] + REDp[R][24+j];
      float o[5];
      chain5(s, sbb[gidx], sbb[4+gidx],
             srow[2][R], srow[3][R], srow[0][R], srow[1][R], o);
      #pragma unroll
      for (int k = 0; k < 5; ++k) kco[R][gsel*5 + k] = o[k];
    }
    __syncthreads();

    // ---- fused z/r phase3: ztp pack, UNSCALED rh in-place into hb, h stash,
    //      |rh|^2 partials -> RED col 7 (reduce7 writes only cols 0-6)
    unsigned ztp[4][2];
    float hvreg[4][4];
    {
      float gvz[4], bvz[4], gvr[4], bvr[4];
      #pragma unroll
      for (int n = 0; n < 4; ++n){
        int C = wc*64 + n*16 + lr;
        gvz[n] = gam[C];      bvz[n] = bet[C];
        gvr[n] = gam[HD + C]; bvr[n] = bet[HD + C];
      }
      #pragma unroll
      for (int q = 0; q < 4; ++q){
        int R = lg*4 + q;
        float KAz=kco[R][0], KBz=kco[R][1], Kbz=kco[R][2], muz=kco[R][3], isz=kco[R][4];
        float KAr=kco[R][5], KBr=kco[R][6], Kbr=kco[R][7], mur=kco[R][8], isr=kco[R][9];
        float acc = 0.f;
        #pragma unroll
        for (int n = 0; n < 4; ++n){
          int C = wc*64 + n*16 + lr;
          float hv = bf2f(hb[swz(R, C)]);
          hvreg[n][q] = hv;
          float lnz = (KAz*Az[n][q] + KBz*Bz[n][q] + Kbz*btz[n] - muz)*isz*gvz[n] + bvz[n];
          unsigned zb = f2bf(sigmoid_f(lnz));
          if ((q & 1) == 0) ztp[n][q>>1] = zb;
          else              ztp[n][q>>1] |= (zb << 16);
          float lnr = (KAr*Ar[n][q] + KBr*Br[n][q] + Kbr*btr[n] - mur)*isr*gvr[n] + bvr[n];
          float rhv = sigmoid_f(lnr) * hv;
          hb[swz(R, C)] = f2bf(rhv);          // in-place, unscaled
          acc = fmaf(rhv, rhv, acc);
        }
        float v2 = sum16_dpp(acc);
        if (lr == 0) REDZ[R][wc*8 + 7] = v2;
      }
    }
    __syncthreads();   // rh + |rh|^2 partials visible

    // ---- all-lane r2 mini-chain (short; off critical path) -> scq ----
    float scq[4];
    {
      int crow = lg*4 + (lr & 3);
      float s0 = REDZ[crow][7] + REDZ[crow][15] + REDZ[crow][23] + REDZ[crow][31];
      float wraw = sqrtf(s0); float wn = fmaxf(wraw, 1e-7f);
      float sv = tanh_f(wn / srow[2][crow] * srow[3][crow]);
      float sc = (wraw <= 1e-7f) ? 0.f : sv / wn;
      float rn = fmaxf((wraw <= 1e-7f) ? 0.f : fabsf(sv), 1e-7f);
      if (wc == 0 && lr < 4){ srow[4][crow] = rn; srow[5][crow] = artanh_f(rn); }
      #pragma unroll
      for (int q = 0; q < 4; ++q) scq[q] = __shfl(sc, (l & 48) + q);
    }

    // ================= h gate: single-stream GEMM on UNSCALED rh ============
    f32x4 Ah[4];
    float bth[4];
    #pragma unroll
    for (int n = 0; n < 4; ++n){
      int C = wc*64 + n*16 + lr;
      bth[n] = bias[HD + C];
      Ah[n] = (f32x4){0.f,0.f,0.f,0.f};
    }
    {
      const unsigned short* wHh = wbhh + 65536;
      #pragma unroll
      for (int s = 0; s < 8; ++s){
        int idx = lr*HD + (((4*s + lg) ^ (lr & 7)) << 3);
        bf16x8 ar = *(const bf16x8*)&hb[idx];
        #pragma unroll
        for (int n = 0; n < 4; ++n){
          int off = (((wc*4 + n)*8 + s)*64 + l)*8;
          bf16x8 bh = *(const bf16x8*)(wHh + off);
          Ah[n] = __builtin_amdgcn_mfma_f32_16x16x32_bf16(ar, bh, Ah[n], 0, 0, 0);
        }
      }
    }
    // fold mobius row-scale into Ah (row scaling commutes with W*v)
    #pragma unroll
    for (int n = 0; n < 4; ++n)
      #pragma unroll
      for (int q = 0; q < 4; ++q) Ah[n][q] *= scq[q];
    reduce7(Ah, Bh, bth, REDZ, wc, lr, lg);
    __syncthreads();
    if (t < BM){
      int R = t;
      float s[7];
      #pragma unroll
      for (int j = 0; j < 7; ++j)
        s[j] = REDZ[R][j] + REDZ[R][8+j] + REDZ[R][16+j] + REDZ[R][24+j];
      float o[5];
      chain5(s, sbb[1], sbb[5],
             srow[4][R], srow[5][R], srow[0][R], srow[1][R], o);
      #pragma unroll
      for (int k = 0; k < 5; ++k) kco[R][k] = o[k];
    }
    __syncthreads();
    // h phase3: u = tanh(ln) into Ah, |u|^2 partials
    {
      float gvh[4], bvh[4];
      #pragma unroll
      for (int n = 0; n < 4; ++n){
        int C = wc*64 + n*16 + lr;
        gvh[n] = gam[2*HD + C]; bvh[n] = bet[2*HD + C];
      }
      #pragma unroll
      for (int q = 0; q < 4; ++q){
        int R = lg*4 + q;
        float KA=kco[R][0], KB=kco[R][1], Kb=kco[R][2], mu=kco[R][3], is=kco[R][4];
        float acc = 0.f;
        #pragma unroll
        for (int n = 0; n < 4; ++n){
          float ln = (KA*Ah[n][q] + KB*Bh[n][q] + Kb*bth[n] - mu)*is*gvh[n] + bvh[n];
          float uv = tanh_f(ln);
          Ah[n][q] = uv;
          acc = fmaf(uv, uv, acc);
        }
        float v2 = sum16_dpp(acc);
        if (lr == 0) REDZ[R][wc*8] = v2;
      }
    }
    __syncthreads();
    if (t < BM){
      int R = t;
      float s0 = REDZ[R][0] + REDZ[R][8] + REDZ[R][16] + REDZ[R][24];
      float unraw = sqrtf(s0);
      float un = fmaxf(unraw, 1e-7f);
      float es = tanh_f(un) / un;
      float htn = fmaxf(es * unraw, 1e-7f);
      kco[R][0] = es; srow[6][R] = htn; srow[7][R] = artanh_f(htn);
    }
    __syncthreads();

    // ================= final combine =================
    #pragma unroll
    for (int q = 0; q < 4; ++q){
      int R = lg*4 + q;
      float es = kco[R][0];
      float a1 = 0.f, a2 = 0.f, a12 = 0.f;
      #pragma unroll
      for (int n = 0; n < 4; ++n){
        unsigned zp = ztp[n][q >> 1];
        float zv = __uint_as_float((q & 1) ? (zp & 0xFFFF0000u) : (zp << 16));
        float w2v = zv * es * Ah[n][q];
        float w1v = (1.f - zv) * hvreg[n][q];
        Ah[n][q] = w2v;
        Bh[n][q] = w1v;
        a1 = fmaf(w1v, w1v, a1); a2 = fmaf(w2v, w2v, a2); a12 = fmaf(w1v, w2v, a12);
      }
      float v1 = sum16_dpp(a1);
      float v2 = sum16_dpp(a2);
      float v3 = sum16_dpp(a12);
      if (lr == 0){
        REDZ[R][wc*8]   = v1;
        REDZ[R][wc*8+1] = v2;
        REDZ[R][wc*8+2] = v3;
      }
    }
    __syncthreads();
    if (t < BM){
      int R = t;
      float s1  = REDZ[R][0] + REDZ[R][8]  + REDZ[R][16] + REDZ[R][24];
      float s2  = REDZ[R][1] + REDZ[R][9]  + REDZ[R][17] + REDZ[R][25];
      float s12 = REDZ[R][2] + REDZ[R][10] + REDZ[R][18] + REDZ[R][26];
      float raw1 = sqrtf(s1); float n1 = fmaxf(raw1, 1e-7f);
      float ss1 = tanh_f(n1 / srow[2][R] * srow[3][R]);
      float sc1 = (raw1 <= 1e-7f) ? 0.f : ss1 / n1;
      float t1  = (raw1 <= 1e-7f) ? 0.f : ss1*ss1;
      float raw2 = sqrtf(s2); float n2 = fmaxf(raw2, 1e-7f);
      float ss2 = tanh_f(n2 / srow[6][R] * srow[7][R]);
      float sc2 = (raw2 <= 1e-7f) ? 0.f : ss2 / n2;
      float t2  = (raw2 <= 1e-7f) ? 0.f : ss2*ss2;
      float xy = sc1*sc2*s12;
      float ca = 1.f + 2.f*xy + t2;
      float cb = 1.f - t1;
      float den = fmaxf(1.f + 2.f*xy + t1*t2, 1e-15f);
      kco[R][0] = ca*sc1/den;
      kco[R][1] = cb*sc2/den;
    }
    __syncthreads();
    #pragma unroll
    for (int q = 0; q < 4; ++q){
      int R = lg*4 + q;
      float cw1 = kco[R][0], cw2 = kco[R][1];
      #pragma unroll
      for (int n = 0; n < 4; ++n){
        int C = wc*64 + n*16 + lr;
        out[(row0 + R)*HD + C] = cw1*Bh[n][q] + cw2*Ah[n][q];
      }
    }
    // NO loop-end barrier needed: next tile's staging writes xb/hb/spart(REDZ)
    // only; stragglers here read kco + registers — disjoint.
  }
}

extern "C" void kernel_launch(void* const* d_in, const int* in_sizes, int n_in,
                              void* d_out, int out_size, void* d_ws, size_t ws_size,
                              hipStream_t stream){
  const float* x    = (const float*)d_in[0];
  const float* hx   = (const float*)d_in[1];
  const float* Wih  = (const float*)d_in[2];
  const float* Whh  = (const float*)d_in[3];
  const float* bias = (const float*)d_in[4];
  const float* gam  = (const float*)d_in[5];
  const float* bet  = (const float*)d_in[6];
  float* out = (float*)d_out;
  unsigned short* wb = (unsigned short*)d_ws;
  const int B = in_sizes[0] / HD;

  hipLaunchKernelGGL(convert_w_kernel, dim3(192), dim3(256), 0, stream, Wih, Whh, wb);
  hipLaunchKernelGGL(mobius_gru_mfma, dim3(B / (BM * TPB)), dim3(NTH), 0, stream,
                     x, hx, wb, wb + 3*65536, bias, gam, bet, out, B);
}

// Round 16
// 192.035 us; speedup vs baseline: 6.4397x; 6.4397x over previous
//
#include <hip/hip_runtime.h>
#include <math.h>

#define HD  256
#define BM  16
#define NTH 256

typedef __attribute__((ext_vector_type(8))) short bf16x8;
typedef __attribute__((ext_vector_type(4))) float f32x4;

__device__ __forceinline__ float rcp_f(float x){ return __builtin_amdgcn_rcpf(x); }
__device__ __forceinline__ float tanh_f(float x){
  float ax = fabsf(x);
  float e  = __expf(-2.f*ax);
  float t  = (1.f - e) * rcp_f(1.f + e);
  return copysignf(t, x);
}
__device__ __forceinline__ float artanh_f(float v){
  v = fminf(fmaxf(v, -1.f + 1e-7f), 1.f - 1e-7f);
  return 0.5f * __logf((1.f + v) * rcp_f(1.f - v));
}
__device__ __forceinline__ float sigmoid_f(float v){ return rcp_f(1.f + __expf(-v)); }
__device__ __forceinline__ unsigned short f2bf(float f){
  unsigned u = __float_as_uint(f);
  u += 0x7FFFu + ((u >> 16) & 1u);
  return (unsigned short)(u >> 16);
}
__device__ __forceinline__ float bf2f(unsigned short h){
  return __uint_as_float(((unsigned)h) << 16);
}
__device__ __forceinline__ int swz(int R, int C){
  return R*HD + (((C >> 3) ^ (R & 7)) << 3) + (C & 7);
}

// ---- 16-lane row-sum via DPP row_ror (pure VALU; replaces ds_bpermute
//      xor-butterfly: ~40cy DS-pipe steps -> ~4cy VALU steps, zero DS ops).
//      After 4 steps every lane holds the sum of its 16-lane row. ----
__device__ __forceinline__ float sum16_dpp(float v){
  v += __uint_as_float((unsigned)__builtin_amdgcn_update_dpp(
        0, (int)__float_as_uint(v), 0x121, 0xF, 0xF, false)); // row_ror:1
  v += __uint_as_float((unsigned)__builtin_amdgcn_update_dpp(
        0, (int)__float_as_uint(v), 0x122, 0xF, 0xF, false)); // row_ror:2
  v += __uint_as_float((unsigned)__builtin_amdgcn_update_dpp(
        0, (int)__float_as_uint(v), 0x124, 0xF, 0xF, false)); // row_ror:4
  v += __uint_as_float((unsigned)__builtin_amdgcn_update_dpp(
        0, (int)__float_as_uint(v), 0x128, 0xF, 0xF, false)); // row_ror:8
  return v;
}

// ---- W fp32 -> bf16 in MFMA-fragment order ----
__global__ void convert_w_kernel(const float* __restrict__ Wih,
                                 const float* __restrict__ Whh,
                                 unsigned short* __restrict__ wb){
  int c = blockIdx.x * blockDim.x + threadIdx.x;
  if (c >= 6 * 8192) return;
  int mat = c >> 13;
  int ci  = c & 8191;
  int l = ci & 63, st = ci >> 6;
  int s = st & 7, ct = st >> 3;
  int col = ct * 16 + (l & 15);
  int k0  = s * 32 + (l >> 4) * 8;
  const float* src = (mat < 3) ? (Wih + (size_t)mat * HD * HD)
                               : (Whh + (size_t)(mat - 3) * HD * HD);
  const float* p = src + (size_t)col * HD + k0;
  unsigned short tmp[8];
  #pragma unroll
  for (int j = 0; j < 8; ++j) tmp[j] = f2bf(p[j]);
  *(bf16x8*)(wb + (size_t)mat * 65536 + (size_t)ci * 8) = *(bf16x8*)tmp;
}

// ---- 7-value reduction for one (A,B) gate pair -> RED[R][wc*8+j], j=0..6 ----
__device__ __forceinline__ void reduce7(
    const f32x4* A, const f32x4* B, const float* bt,
    float (*RED)[33], int wc, int lr, int lg){
  float p[7][4];
  #pragma unroll
  for (int q = 0; q < 4; ++q){
    float a2=0.f,b2=0.f,ab=0.f,sA=0.f,sB=0.f,Ab=0.f,Bb=0.f;
    #pragma unroll
    for (int n = 0; n < 4; ++n){
      float ae = A[n][q], be = B[n][q], bv = bt[n];
      a2 = fmaf(ae,ae,a2); b2 = fmaf(be,be,b2); ab = fmaf(ae,be,ab);
      sA += ae; sB += be; Ab = fmaf(ae,bv,Ab); Bb = fmaf(be,bv,Bb);
    }
    p[0][q]=a2; p[1][q]=b2; p[2][q]=ab; p[3][q]=sA; p[4][q]=sB; p[5][q]=Ab; p[6][q]=Bb;
  }
  #pragma unroll
  for (int j = 0; j < 7; ++j)
    #pragma unroll
    for (int q = 0; q < 4; ++q)
      p[j][q] = sum16_dpp(p[j][q]);
  if (lr == 0){
    #pragma unroll
    for (int q = 0; q < 4; ++q){
      int R = lg*4 + q;
      #pragma unroll
      for (int j = 0; j < 7; ++j) RED[R][wc*8 + j] = p[j][q];
    }
  }
}

// ---- once-per-row mobius+LN chain: s[7] -> {KA,KB,Kb,mu,is} ----
__device__ __forceinline__ void chain5(
    const float* s, float bb, float sbs,
    float an, float aa, float bn, float ba, float* o){
  float mraw = sqrtf(s[0]); float mA = fmaxf(mraw, 1e-7f);
  float tA = tanh_f(mA / an * aa);
  float sa  = (mraw <= 1e-7f) ? 0.f : tA / mA;
  float x2a = (mraw <= 1e-7f) ? 0.f : tA*tA;
  float nraw = sqrtf(s[1]); float mB = fmaxf(nraw, 1e-7f);
  float tB = tanh_f(mB / bn * ba);
  float sb_ = (nraw <= 1e-7f) ? 0.f : tB / mB;
  float x2b = (nraw <= 1e-7f) ? 0.f : tB*tB;
  float xy = sa*sb_*s[2];
  float ca = 1.f + 2.f*xy + x2b;
  float cb = 1.f - x2a;
  float den = fmaxf(1.f + 2.f*xy + x2a*x2b, 1e-15f);
  float u = ca*sa/den, v = cb*sb_/den;
  float P2 = u*u*s[0] + 2.f*u*v*s[2] + v*v*s[1];
  float Pb = u*s[5] + v*s[6];
  float sP = u*s[3] + v*s[4];
  float ca2 = 1.f + 2.f*Pb + bb;
  float cb2 = 1.f - P2;
  float den2 = fmaxf(1.f + 2.f*Pb + P2*bb, 1e-15f);
  float pp = ca2/den2, ww = cb2/den2;
  float Q2 = pp*pp*P2 + 2.f*pp*ww*Pb + ww*ww*bb;
  float sQsum = pp*sP + ww*sbs;
  float qn = fmaxf(sqrtf(Q2), 1e-7f);
  float sQ = artanh_f(qn) / qn;
  float mu = sQ*sQsum*(1.f/HD);
  float e2 = sQ*sQ*Q2*(1.f/HD);
  float is = rsqrtf(e2 - mu*mu + 1e-5f);
  o[0] = sQ*pp*u;  o[1] = sQ*pp*v;  o[2] = sQ*ww;
  o[3] = mu;       o[4] = is;
}

// FINAL (R13 revert — session best: 192.7us bench / 224.8us rocprof).
// Design summary from 16 measured rounds:
//  - (256,2) launch-bounds, 2 independent blocks/CU: the UNIQUE no-spill
//    point (every other waves/groups config hit the 128-reg tier + scratch).
//  - fused z+r+x-of-h 5-stream GEMM (R5, +1.5%): one fill/drain, z&r chains
//    concurrent on disjoint threads.
//  - unscaled rh in-place into hb; mobius row-scale folded into Ah post-GEMM
//    (commutes with W*v); short mini-chains all-lane redundant (R10).
//  - ALL in-row reductions via DPP row_ror (sum16_dpp, R13: -10%): the DS
//    pipe's ~400 ds_bpermute ops/thread were the dominant hidden cost.
//  - persistent/multi-tile bodies spill under this compiler (R14/R15) —
//    the barrier-heavy phase chain must be straight-line code.
__global__ __launch_bounds__(NTH, 2) void mobius_gru_mfma(
    const float* __restrict__ x, const float* __restrict__ hx,
    const unsigned short* __restrict__ wbih, const unsigned short* __restrict__ wbhh,
    const float* __restrict__ bias, const float* __restrict__ gam,
    const float* __restrict__ bet, float* __restrict__ out, int B){
  __shared__ unsigned short xb[BM*HD];
  __shared__ unsigned short hb[BM*HD];
  __shared__ float REDZ[BM][33];
  __shared__ float REDR[BM][33];
  __shared__ float kco[BM][10];   // z: 0..4, r: 5..9 (h reuses 0..4)
  __shared__ float srow[8][BM];   // 0:xn 1:xa 2:hn 3:ha 4:rn 5:ra 6:htn 7:hta
  __shared__ float sbb[8];        // [g]=sum b^2, [4+g]=sum b

  const int t  = threadIdx.x;
  const int l  = t & 63;
  const int lr = l & 15, lg = l >> 4;
  const int wc = t >> 6;          // 4 waves, one 64-col slice each
  const size_t row0 = (size_t)blockIdx.x * BM;

  // ---- stage x,hx -> bf16 swizzled LDS + norm partials (spart overlays REDZ) ----
  {
    float* spart = &REDZ[0][0];   // [0,256): x partials, [256,512): h partials
    int r = t >> 4, seg = t & 15;
    const float* xp = x  + (row0 + r)*HD + seg*16;
    const float* hp = hx + (row0 + r)*HD + seg*16;
    float sx = 0.f, sh = 0.f;
    #pragma unroll
    for (int i = 0; i < 4; ++i){
      int c = seg*16 + i*4;
      int di = swz(r, c);
      float4 v = *(const float4*)(xp + i*4);
      sx += v.x*v.x + v.y*v.y + v.z*v.z + v.w*v.w;
      ushort4 o = { f2bf(v.x), f2bf(v.y), f2bf(v.z), f2bf(v.w) };
      *(ushort4*)&xb[di] = o;
      v = *(const float4*)(hp + i*4);
      sh += v.x*v.x + v.y*v.y + v.z*v.z + v.w*v.w;
      ushort4 o2 = { f2bf(v.x), f2bf(v.y), f2bf(v.z), f2bf(v.w) };
      *(ushort4*)&hb[di] = o2;
    }
    spart[r*16 + seg] = sx; spart[256 + r*16 + seg] = sh;
  }
  if (t >= 64 && t < 256){
    int g = (t >> 6) - 1;
    float4 b4 = *(const float4*)&bias[g*HD + (t & 63)*4];
    float p2 = b4.x*b4.x + b4.y*b4.y + b4.z*b4.z + b4.w*b4.w;
    float ps = b4.x + b4.y + b4.z + b4.w;
    #pragma unroll
    for (int m = 1; m <= 32; m <<= 1){ p2 += __shfl_xor(p2, m); ps += __shfl_xor(ps, m); }
    if ((t & 63) == 0){ sbb[g] = p2; sbb[4+g] = ps; }
  }
  __syncthreads();
  if (t < BM){
    float* spart = &REDZ[0][0];
    float sx = 0.f, sh = 0.f;
    #pragma unroll
    for (int i = 0; i < 16; ++i){ sx += spart[t*16 + i]; sh += spart[256 + t*16 + i]; }
    float xn = fmaxf(sqrtf(sx), 1e-7f);
    float hn = fmaxf(sqrtf(sh), 1e-7f);
    srow[0][t] = xn; srow[1][t] = artanh_f(xn);
    srow[2][t] = hn; srow[3][t] = artanh_f(hn);
  }
  __syncthreads();

  // ================= fused z + r + x-of-h GEMM (5 weight streams) =========
  f32x4 Az[4], Bz[4], Ar[4], Br[4], Bh[4];
  float btz[4], btr[4];
  #pragma unroll
  for (int n = 0; n < 4; ++n){
    int C = wc*64 + n*16 + lr;
    btz[n] = bias[2*HD + C];
    btr[n] = bias[C];
    Az[n] = (f32x4){0.f,0.f,0.f,0.f}; Bz[n] = (f32x4){0.f,0.f,0.f,0.f};
    Ar[n] = (f32x4){0.f,0.f,0.f,0.f}; Br[n] = (f32x4){0.f,0.f,0.f,0.f};
    Bh[n] = (f32x4){0.f,0.f,0.f,0.f};
  }
  {
    const unsigned short* wHz = wbhh + 2*65536;
    const unsigned short* wXz = wbih + 2*65536;
    const unsigned short* wHr = wbhh;
    const unsigned short* wXr = wbih;
    const unsigned short* wXh = wbih + 65536;
    #pragma unroll
    for (int s = 0; s < 8; ++s){
      int idx = lr*HD + (((4*s + lg) ^ (lr & 7)) << 3);
      bf16x8 ah = *(const bf16x8*)&hb[idx];
      bf16x8 ax = *(const bf16x8*)&xb[idx];
      #pragma unroll
      for (int n = 0; n < 4; ++n){
        int off = (((wc*4 + n)*8 + s)*64 + l)*8;
        bf16x8 bhz = *(const bf16x8*)(wHz + off);
        bf16x8 bxz = *(const bf16x8*)(wXz + off);
        bf16x8 bhr = *(const bf16x8*)(wHr + off);
        bf16x8 bxr = *(const bf16x8*)(wXr + off);
        bf16x8 bxh = *(const bf16x8*)(wXh + off);
        Az[n] = __builtin_amdgcn_mfma_f32_16x16x32_bf16(ah, bhz, Az[n], 0, 0, 0);
        Bz[n] = __builtin_amdgcn_mfma_f32_16x16x32_bf16(ax, bxz, Bz[n], 0, 0, 0);
        Ar[n] = __builtin_amdgcn_mfma_f32_16x16x32_bf16(ah, bhr, Ar[n], 0, 0, 0);
        Br[n] = __builtin_amdgcn_mfma_f32_16x16x32_bf16(ax, bxr, Br[n], 0, 0, 0);
        Bh[n] = __builtin_amdgcn_mfma_f32_16x16x32_bf16(ax, bxh, Bh[n], 0, 0, 0);
      }
    }
  }
  reduce7(Az, Bz, btz, REDZ, wc, lr, lg);
  reduce7(Ar, Br, btr, REDR, wc, lr, lg);
  __syncthreads();
  // z chain on t<16, r chain on 16<=t<32 — same code path, disjoint threads
  if (t < 32){
    int R = t & 15, gsel = t >> 4;            // 0: z (gidx 2), 1: r (gidx 0)
    float (*REDp)[33] = gsel ? REDR : REDZ;
    int gidx = gsel ? 0 : 2;
    float s[7];
    #pragma unroll
    for (int j = 0; j < 7; ++j)
      s[j] = REDp[R][j] + REDp[R][8+j] + REDp[R][16+j] + REDp[R][24+j];
    float o[5];
    chain5(s, sbb[gidx], sbb[4+gidx],
           srow[2][R], srow[3][R], srow[0][R], srow[1][R], o);
    #pragma unroll
    for (int k = 0; k < 5; ++k) kco[R][gsel*5 + k] = o[k];
  }
  __syncthreads();

  // ---- fused z/r phase3: ztp pack, UNSCALED rh in-place into hb, h stash,
  //      |rh|^2 partials -> RED col 7 (reduce7 writes only cols 0-6)
  unsigned ztp[4][2];
  float hvreg[4][4];
  {
    float gvz[4], bvz[4], gvr[4], bvr[4];
    #pragma unroll
    for (int n = 0; n < 4; ++n){
      int C = wc*64 + n*16 + lr;
      gvz[n] = gam[C];      bvz[n] = bet[C];
      gvr[n] = gam[HD + C]; bvr[n] = bet[HD + C];
    }
    #pragma unroll
    for (int q = 0; q < 4; ++q){
      int R = lg*4 + q;
      float KAz=kco[R][0], KBz=kco[R][1], Kbz=kco[R][2], muz=kco[R][3], isz=kco[R][4];
      float KAr=kco[R][5], KBr=kco[R][6], Kbr=kco[R][7], mur=kco[R][8], isr=kco[R][9];
      float acc = 0.f;
      #pragma unroll
      for (int n = 0; n < 4; ++n){
        int C = wc*64 + n*16 + lr;
        float hv = bf2f(hb[swz(R, C)]);
        hvreg[n][q] = hv;
        float lnz = (KAz*Az[n][q] + KBz*Bz[n][q] + Kbz*btz[n] - muz)*isz*gvz[n] + bvz[n];
        unsigned zb = f2bf(sigmoid_f(lnz));
        if ((q & 1) == 0) ztp[n][q>>1] = zb;
        else              ztp[n][q>>1] |= (zb << 16);
        float lnr = (KAr*Ar[n][q] + KBr*Br[n][q] + Kbr*btr[n] - mur)*isr*gvr[n] + bvr[n];
        float rhv = sigmoid_f(lnr) * hv;
        hb[swz(R, C)] = f2bf(rhv);          // in-place, unscaled
        acc = fmaf(rhv, rhv, acc);
      }
      float v2 = sum16_dpp(acc);
      if (lr == 0) REDZ[R][wc*8 + 7] = v2;
    }
  }
  __syncthreads();   // rh + |rh|^2 partials visible

  // ---- all-lane r2 mini-chain (short; off critical path) -> scq ----
  float scq[4];
  {
    int crow = lg*4 + (lr & 3);
    float s0 = REDZ[crow][7] + REDZ[crow][15] + REDZ[crow][23] + REDZ[crow][31];
    float wraw = sqrtf(s0); float wn = fmaxf(wraw, 1e-7f);
    float sv = tanh_f(wn / srow[2][crow] * srow[3][crow]);
    float sc = (wraw <= 1e-7f) ? 0.f : sv / wn;
    float rn = fmaxf((wraw <= 1e-7f) ? 0.f : fabsf(sv), 1e-7f);
    if (wc == 0 && lr < 4){ srow[4][crow] = rn; srow[5][crow] = artanh_f(rn); }
    #pragma unroll
    for (int q = 0; q < 4; ++q) scq[q] = __shfl(sc, (l & 48) + q);
  }

  // ================= h gate: single-stream GEMM on UNSCALED rh ============
  f32x4 Ah[4];
  float bth[4];
  #pragma unroll
  for (int n = 0; n < 4; ++n){
    int C = wc*64 + n*16 + lr;
    bth[n] = bias[HD + C];
    Ah[n] = (f32x4){0.f,0.f,0.f,0.f};
  }
  {
    const unsigned short* wHh = wbhh + 65536;
    #pragma unroll
    for (int s = 0; s < 8; ++s){
      int idx = lr*HD + (((4*s + lg) ^ (lr & 7)) << 3);
      bf16x8 ar = *(const bf16x8*)&hb[idx];
      #pragma unroll
      for (int n = 0; n < 4; ++n){
        int off = (((wc*4 + n)*8 + s)*64 + l)*8;
        bf16x8 bh = *(const bf16x8*)(wHh + off);
        Ah[n] = __builtin_amdgcn_mfma_f32_16x16x32_bf16(ar, bh, Ah[n], 0, 0, 0);
      }
    }
  }
  // fold mobius row-scale into Ah (row scaling commutes with W*v)
  #pragma unroll
  for (int n = 0; n < 4; ++n)
    #pragma unroll
    for (int q = 0; q < 4; ++q) Ah[n][q] *= scq[q];
  reduce7(Ah, Bh, bth, REDZ, wc, lr, lg);
  __syncthreads();
  if (t < BM){
    int R = t;
    float s[7];
    #pragma unroll
    for (int j = 0; j < 7; ++j)
      s[j] = REDZ[R][j] + REDZ[R][8+j] + REDZ[R][16+j] + REDZ[R][24+j];
    float o[5];
    chain5(s, sbb[1], sbb[5],
           srow[4][R], srow[5][R], srow[0][R], srow[1][R], o);
    #pragma unroll
    for (int k = 0; k < 5; ++k) kco[R][k] = o[k];
  }
  __syncthreads();
  // h phase3: u = tanh(ln) into Ah, |u|^2 partials
  {
    float gvh[4], bvh[4];
    #pragma unroll
    for (int n = 0; n < 4; ++n){
      int C = wc*64 + n*16 + lr;
      gvh[n] = gam[2*HD + C]; bvh[n] = bet[2*HD + C];
    }
    #pragma unroll
    for (int q = 0; q < 4; ++q){
      int R = lg*4 + q;
      float KA=kco[R][0], KB=kco[R][1], Kb=kco[R][2], mu=kco[R][3], is=kco[R][4];
      float acc = 0.f;
      #pragma unroll
      for (int n = 0; n < 4; ++n){
        float ln = (KA*Ah[n][q] + KB*Bh[n][q] + Kb*bth[n] - mu)*is*gvh[n] + bvh[n];
        float uv = tanh_f(ln);
        Ah[n][q] = uv;
        acc = fmaf(uv, uv, acc);
      }
      float v2 = sum16_dpp(acc);
      if (lr == 0) REDZ[R][wc*8] = v2;
    }
  }
  __syncthreads();
  if (t < BM){
    int R = t;
    float s0 = REDZ[R][0] + REDZ[R][8] + REDZ[R][16] + REDZ[R][24];
    float unraw = sqrtf(s0);
    float un = fmaxf(unraw, 1e-7f);
    float es = tanh_f(un) / un;
    float htn = fmaxf(es * unraw, 1e-7f);
    kco[R][0] = es; srow[6][R] = htn; srow[7][R] = artanh_f(htn);
  }
  __syncthreads();

  // ================= final combine =================
  #pragma unroll
  for (int q = 0; q < 4; ++q){
    int R = lg*4 + q;
    float es = kco[R][0];
    float a1 = 0.f, a2 = 0.f, a12 = 0.f;
    #pragma unroll
    for (int n = 0; n < 4; ++n){
      unsigned zp = ztp[n][q >> 1];
      float zv = __uint_as_float((q & 1) ? (zp & 0xFFFF0000u) : (zp << 16));
      float w2v = zv * es * Ah[n][q];
      float w1v = (1.f - zv) * hvreg[n][q];
      Ah[n][q] = w2v;
      Bh[n][q] = w1v;
      a1 = fmaf(w1v, w1v, a1); a2 = fmaf(w2v, w2v, a2); a12 = fmaf(w1v, w2v, a12);
    }
    float v1 = sum16_dpp(a1);
    float v2 = sum16_dpp(a2);
    float v3 = sum16_dpp(a12);
    if (lr == 0){
      REDZ[R][wc*8]   = v1;
      REDZ[R][wc*8+1] = v2;
      REDZ[R][wc*8+2] = v3;
    }
  }
  __syncthreads();
  if (t < BM){
    int R = t;
    float s1  = REDZ[R][0] + REDZ[R][8]  + REDZ[R][16] + REDZ[R][24];
    float s2  = REDZ[R][1] + REDZ[R][9]  + REDZ[R][17] + REDZ[R][25];
    float s12 = REDZ[R][2] + REDZ[R][10] + REDZ[R][18] + REDZ[R][26];
    float raw1 = sqrtf(s1); float n1 = fmaxf(raw1, 1e-7f);
    float ss1 = tanh_f(n1 / srow[2][R] * srow[3][R]);
    float sc1 = (raw1 <= 1e-7f) ? 0.f : ss1 / n1;
    float t1  = (raw1 <= 1e-7f) ? 0.f : ss1*ss1;
    float raw2 = sqrtf(s2); float n2 = fmaxf(raw2, 1e-7f);
    float ss2 = tanh_f(n2 / srow[6][R] * srow[7][R]);
    float sc2 = (raw2 <= 1e-7f) ? 0.f : ss2 / n2;
    float t2  = (raw2 <= 1e-7f) ? 0.f : ss2*ss2;
    float xy = sc1*sc2*s12;
    float ca = 1.f + 2.f*xy + t2;
    float cb = 1.f - t1;
    float den = fmaxf(1.f + 2.f*xy + t1*t2, 1e-15f);
    kco[R][0] = ca*sc1/den;
    kco[R][1] = cb*sc2/den;
  }
  __syncthreads();
  #pragma unroll
  for (int q = 0; q < 4; ++q){
    int R = lg*4 + q;
    float cw1 = kco[R][0], cw2 = kco[R][1];
    #pragma unroll
    for (int n = 0; n < 4; ++n){
      int C = wc*64 + n*16 + lr;
      out[(row0 + R)*HD + C] = cw1*Bh[n][q] + cw2*Ah[n][q];
    }
  }
}

extern "C" void kernel_launch(void* const* d_in, const int* in_sizes, int n_in,
                              void* d_out, int out_size, void* d_ws, size_t ws_size,
                              hipStream_t stream){
  const float* x    = (const float*)d_in[0];
  const float* hx   = (const float*)d_in[1];
  const float* Wih  = (const float*)d_in[2];
  const float* Whh  = (const float*)d_in[3];
  const float* bias = (const float*)d_in[4];
  const float* gam  = (const float*)d_in[5];
  const float* bet  = (const float*)d_in[6];
  float* out = (float*)d_out;
  unsigned short* wb = (unsigned short*)d_ws;
  const int B = in_sizes[0] / HD;

  hipLaunchKernelGGL(convert_w_kernel, dim3(192), dim3(256), 0, stream, Wih, Whh, wb);
  hipLaunchKernelGGL(mobius_gru_mfma, dim3(B / BM), dim3(NTH), 0, stream,
                     x, hx, wb, wb + 3*65536, bias, gam, bet, out, B);
}